// Round 4
// baseline (287.277 us; speedup 1.0000x reference)
//
#include <hip/hip_runtime.h>

#define N_ROWS 32768
#define DIM    256
#define KCODES 2048
#define CSPLIT 2                              // code halves per row-block
#define CPB    (KCODES / CSPLIT)              // 1024 codes per block
#define PASSES (CPB / 256)                    // 4 passes of 256 codes

typedef unsigned short ushort_t;
typedef __attribute__((ext_vector_type(8)))  short bf16x8;
typedef __attribute__((ext_vector_type(16))) float f32x16;

__device__ __forceinline__ unsigned int f2bf(float f) {
    union { float f; unsigned int u; } v; v.f = f;
    unsigned int r = v.u + 0x7FFFu + ((v.u >> 16) & 1u);   // RNE (inputs finite)
    return r >> 16;
}

// ---------------- prologue: cb -> bf16, halfcn = 0.5*||c||^2, zero loss ---------
__global__ void prep_cb(const float* __restrict__ cb, ushort_t* __restrict__ cbb,
                        float* __restrict__ halfcn, float* __restrict__ loss) {
    const int code = blockIdx.x;
    const int t = threadIdx.x;               // 256 threads = D
    if (code == 0 && t == 0) *loss = 0.0f;
    float v = cb[code * DIM + t];
    cbb[code * DIM + t] = (ushort_t)f2bf(v);
    float s = v * v;
    #pragma unroll
    for (int o = 32; o > 0; o >>= 1) s += __shfl_down(s, o, 64);
    __shared__ float red[4];
    if ((t & 63) == 0) red[t >> 6] = s;
    __syncthreads();
    if (t == 0) halfcn[code] = 0.5f * (red[0] + red[1] + red[2] + red[3]);
}

// ---------------- main: 64 rows x 1024 codes, barrier-free K-loop ----------------
// score(n,k) = x_n . c_k - 0.5||c_k||^2 ; argmax score == argmin dist.
// A (64 rows x 256k bf16) persistent in LDS, staged once (fp32->bf16 in-block).
// B fragments loaded straight from global (codebook bf16 is L2-resident) into
// VGPRs — no LDS staging, no __syncthreads in the hot loop.
__global__ __launch_bounds__(256, 3) void argmin_mfma(
        const float* __restrict__ x, const ushort_t* __restrict__ cbb,
        const float* __restrict__ halfcn, float* __restrict__ part) {
    __shared__ char As[8][4096];     // [k-chunk][64 rows x 64B], XOR-swizzled 16B pieces
    __shared__ float red[64][4];

    const int t    = threadIdx.x;
    const int lane = t & 63;
    const int w    = t >> 6;         // wave 0..3 -> 64-code group within a 256 pass-tile
    const int l32  = lane & 31;
    const int h    = lane >> 5;
    const int row0 = blockIdx.y * 64;
    const int cg0  = blockIdx.x * CPB;

    // ---- stage A once: fp32 x -> bf16 LDS, swizzled 16B pieces ----
    {
        const int r  = t >> 2;                // 0..63
        const int p  = t & 3;                 // piece 0..3 within 64B row-chunk
        const int sp = p ^ ((r >> 1) & 3);    // swizzled store position
        #pragma unroll
        for (int kc = 0; kc < 8; kc++) {
            const float* src = x + (size_t)(row0 + r) * DIM + kc * 32 + p * 8;
            float4 v0 = *(const float4*)src;
            float4 v1 = *(const float4*)(src + 4);
            uint4 o;
            o.x = f2bf(v0.x) | (f2bf(v0.y) << 16);
            o.y = f2bf(v0.z) | (f2bf(v0.w) << 16);
            o.z = f2bf(v1.x) | (f2bf(v1.y) << 16);
            o.w = f2bf(v1.z) | (f2bf(v1.w) << 16);
            *(uint4*)(As[kc] + r * 64 + sp * 16) = o;
        }
    }

    // ---- bias preload: 0.5||c||^2 for this wave's codes across all passes ----
    float hcv[PASSES][2];
    #pragma unroll
    for (int p = 0; p < PASSES; p++)
        #pragma unroll
        for (int ct = 0; ct < 2; ct++)
            hcv[p][ct] = halfcn[cg0 + p * 256 + w * 64 + ct * 32 + l32];

    // ---- B base pointers (per-lane 16B frag loads, k-contiguous) ----
    const ushort_t* bbase[2];
    #pragma unroll
    for (int ct = 0; ct < 2; ct++)
        bbase[ct] = cbb + (size_t)(cg0 + w * 64 + ct * 32 + l32) * DIM + h * 8;

    const int fa  = (l32 >> 1) & 3;
    const int pk0 = ((0 + h) ^ fa) * 16;     // ks=0 piece offset in swizzled row
    const int pk1 = ((2 + h) ^ fa) * 16;     // ks=1 piece offset
    const int ar0 = (0 * 32 + l32) * 64;     // rt=0 row byte offset
    const int ar1 = (1 * 32 + l32) * 64;     // rt=1

    float mp[2][16];
    #pragma unroll
    for (int rt = 0; rt < 2; rt++)
        #pragma unroll
        for (int r = 0; r < 16; r++) mp[rt][r] = -3.0e38f;

    __syncthreads();   // A staged; the ONLY barrier before the epilogue

    for (int p = 0; p < PASSES; ++p) {
        f32x16 acc[2][2];
        #pragma unroll
        for (int rt = 0; rt < 2; rt++)
            #pragma unroll
            for (int ct = 0; ct < 2; ct++)
                #pragma unroll
                for (int r = 0; r < 16; r++) acc[rt][ct][r] = -hcv[p][ct];

        const ushort_t* bp0 = bbase[0] + (size_t)p * 256 * DIM;
        const ushort_t* bp1 = bbase[1] + (size_t)p * 256 * DIM;

        #pragma unroll
        for (int kc = 0; kc < 8; ++kc) {
            bf16x8 af[2][2], bfr[2][2];
            af[0][0] = *(const bf16x8*)(As[kc] + ar0 + pk0);
            af[0][1] = *(const bf16x8*)(As[kc] + ar0 + pk1);
            af[1][0] = *(const bf16x8*)(As[kc] + ar1 + pk0);
            af[1][1] = *(const bf16x8*)(As[kc] + ar1 + pk1);
            bfr[0][0] = *(const bf16x8*)(bp0 + kc * 32);
            bfr[0][1] = *(const bf16x8*)(bp0 + kc * 32 + 16);
            bfr[1][0] = *(const bf16x8*)(bp1 + kc * 32);
            bfr[1][1] = *(const bf16x8*)(bp1 + kc * 32 + 16);
            #pragma unroll
            for (int ks = 0; ks < 2; ks++)
                #pragma unroll
                for (int rt = 0; rt < 2; rt++)
                    #pragma unroll
                    for (int ct = 0; ct < 2; ct++)
                        acc[rt][ct] = __builtin_amdgcn_mfma_f32_32x32x16_bf16(
                            af[rt][ks], bfr[ct][ks], acc[rt][ct], 0, 0, 0);
        }

        // fold pass into running max (pack 11-bit code id into low mantissa bits)
        #pragma unroll
        for (int ct = 0; ct < 2; ct++) {
            const unsigned code = (unsigned)(cg0 + p * 256 + w * 64 + ct * 32 + l32);
            #pragma unroll
            for (int rt = 0; rt < 2; rt++)
                #pragma unroll
                for (int r = 0; r < 16; r++) {
                    unsigned u = (__float_as_uint(acc[rt][ct][r]) & 0xFFFFF800u) | code;
                    mp[rt][r] = fmaxf(mp[rt][r], __uint_as_float(u));
                }
        }
    }

    // ---- cross-lane argmax over the 32 lanes sharing each output row ----
    #pragma unroll
    for (int m = 1; m <= 16; m <<= 1)
        #pragma unroll
        for (int rt = 0; rt < 2; rt++)
            #pragma unroll
            for (int r = 0; r < 16; r++)
                mp[rt][r] = fmaxf(mp[rt][r], __shfl_xor(mp[rt][r], m, 64));

    if (l32 == 0) {
        #pragma unroll
        for (int rt = 0; rt < 2; rt++)
            #pragma unroll
            for (int r = 0; r < 16; r++) {
                const int row = rt * 32 + (r & 3) + 8 * (r >> 2) + 4 * h;
                red[row][w] = mp[rt][r];
            }
    }
    __syncthreads();
    if (t < 64) {
        float b0 = fmaxf(fmaxf(red[t][0], red[t][1]), fmaxf(red[t][2], red[t][3]));
        part[(size_t)(row0 + t) * CSPLIT + blockIdx.x] = b0;
    }
}

// ---------------- epilogue: reduce partials + gather + loss ---------------------
__global__ void finish_kernel(const float* __restrict__ x, const float* __restrict__ cb,
                              const float* __restrict__ part, float* __restrict__ out,
                              float* __restrict__ loss) {
    const int t = threadIdx.x;    // 256 threads cover D
    float lsum = 0.0f;
    #pragma unroll
    for (int r = 0; r < 16; r++) {
        const int row = blockIdx.x * 16 + r;
        float2 pr = *(const float2*)&part[(size_t)row * CSPLIT];
        float b = fmaxf(pr.x, pr.y);
        const int code = (int)(__float_as_uint(b) & 2047u);
        const float c  = cb[(size_t)code * DIM + t];
        const float xv = x[(size_t)row * DIM + t];
        out[(size_t)row * DIM + t] = c;
        const float diff = xv - c;
        lsum += diff * diff;
    }
    #pragma unroll
    for (int o = 32; o > 0; o >>= 1) lsum += __shfl_down(lsum, o, 64);
    __shared__ float red[4];
    if ((t & 63) == 0) red[t >> 6] = lsum;
    __syncthreads();
    if (t == 0) {
        const float scale = 1.25f / (float)((size_t)N_ROWS * DIM);  // (beta+1)/(N*D)
        atomicAdd(loss, (red[0] + red[1] + red[2] + red[3]) * scale);
    }
}

extern "C" void kernel_launch(void* const* d_in, const int* in_sizes, int n_in,
                              void* d_out, int out_size, void* d_ws, size_t ws_size,
                              hipStream_t stream) {
    const float* x  = (const float*)d_in[0];
    const float* cb = (const float*)d_in[1];
    float* out  = (float*)d_out;
    float* loss = out + (size_t)N_ROWS * DIM;

    char* ws = (char*)d_ws;
    ushort_t* cbb    = (ushort_t*)ws;                               // 1 MB
    float*    halfcn = (float*)(ws + (size_t)KCODES * DIM * 2);     // 8 KB
    float*    part   = (float*)(ws + (size_t)KCODES * DIM * 2 + KCODES * 4);  // 256 KB

    prep_cb<<<KCODES, 256, 0, stream>>>(cb, cbb, halfcn, loss);
    argmin_mfma<<<dim3(CSPLIT, N_ROWS / 64), 256, 0, stream>>>(x, cbb, halfcn, part);
    finish_kernel<<<N_ROWS / 16, 256, 0, stream>>>(x, cb, part, out, loss);
}

// Round 5
// 190.020 us; speedup vs baseline: 1.5118x; 1.5118x over previous
//
#include <hip/hip_runtime.h>

#define N_ROWS 32768
#define DIM    256
#define KCODES 2048
#define CSPLIT 2                              // code halves per row-block
#define CPB    (KCODES / CSPLIT)              // 1024 codes per block
#define PASSES (CPB / 256)                    // 4 passes of 256 codes

typedef unsigned short ushort_t;
typedef __attribute__((ext_vector_type(8)))  short bf16x8;
typedef __attribute__((ext_vector_type(16))) float f32x16;

__device__ __forceinline__ unsigned int f2bf(float f) {
    union { float f; unsigned int u; } v; v.f = f;
    unsigned int r = v.u + 0x7FFFu + ((v.u >> 16) & 1u);   // RNE (inputs finite)
    return r >> 16;
}

// ---------------- prologue: cb -> bf16, halfcn = 0.5*||c||^2, zero loss ---------
__global__ void prep_cb(const float* __restrict__ cb, ushort_t* __restrict__ cbb,
                        float* __restrict__ halfcn, float* __restrict__ loss) {
    const int code = blockIdx.x;
    const int t = threadIdx.x;               // 256 threads = D
    if (code == 0 && t == 0) *loss = 0.0f;
    float v = cb[code * DIM + t];
    cbb[code * DIM + t] = (ushort_t)f2bf(v);
    float s = v * v;
    #pragma unroll
    for (int o = 32; o > 0; o >>= 1) s += __shfl_down(s, o, 64);
    __shared__ float red[4];
    if ((t & 63) == 0) red[t >> 6] = s;
    __syncthreads();
    if (t == 0) halfcn[code] = 0.5f * (red[0] + red[1] + red[2] + red[3]);
}

// ---------------- main: 64 rows x 1024 codes, barrier-free K-loop ----------------
// score(n,k) = x_n . c_k - 0.5||c_k||^2 ; argmax score == argmin dist.
// A (64 rows x 256k bf16) persistent in LDS, staged once (fp32->bf16 in-block).
// B fragments loaded straight from global (codebook bf16 is L2-resident) into
// VGPRs — no LDS staging, no __syncthreads in the hot loop.
// launch_bounds(256,2): VGPR cap 256 — R4's (256,3) cap of ~170 caused massive
// scratch spills (193 MB WRITE_SIZE).
__global__ __launch_bounds__(256, 2) void argmin_mfma(
        const float* __restrict__ x, const ushort_t* __restrict__ cbb,
        const float* __restrict__ halfcn, float* __restrict__ part) {
    __shared__ char As[8][4096];     // [k-chunk][64 rows x 64B], XOR-swizzled 16B pieces
    __shared__ float red[64][4];

    const int t    = threadIdx.x;
    const int lane = t & 63;
    const int w    = t >> 6;         // wave 0..3 -> 64-code group within a 256 pass-tile
    const int l32  = lane & 31;
    const int h    = lane >> 5;
    const int row0 = blockIdx.y * 64;
    const int cg0  = blockIdx.x * CPB;

    // ---- stage A once: fp32 x -> bf16 LDS, swizzled 16B pieces ----
    {
        const int r  = t >> 2;                // 0..63
        const int p  = t & 3;                 // piece 0..3 within 64B row-chunk
        const int sp = p ^ ((r >> 1) & 3);    // swizzled store position
        #pragma unroll
        for (int kc = 0; kc < 8; kc++) {
            const float* src = x + (size_t)(row0 + r) * DIM + kc * 32 + p * 8;
            float4 v0 = *(const float4*)src;
            float4 v1 = *(const float4*)(src + 4);
            uint4 o;
            o.x = f2bf(v0.x) | (f2bf(v0.y) << 16);
            o.y = f2bf(v0.z) | (f2bf(v0.w) << 16);
            o.z = f2bf(v1.x) | (f2bf(v1.y) << 16);
            o.w = f2bf(v1.z) | (f2bf(v1.w) << 16);
            *(uint4*)(As[kc] + r * 64 + sp * 16) = o;
        }
    }

    // ---- bias preload: 0.5||c||^2 for this wave's codes across all passes ----
    float hcv[PASSES][2];
    #pragma unroll
    for (int p = 0; p < PASSES; p++)
        #pragma unroll
        for (int ct = 0; ct < 2; ct++)
            hcv[p][ct] = halfcn[cg0 + p * 256 + w * 64 + ct * 32 + l32];

    // ---- B base pointers (per-lane 16B frag loads, k-contiguous) ----
    const ushort_t* bbase[2];
    #pragma unroll
    for (int ct = 0; ct < 2; ct++)
        bbase[ct] = cbb + (size_t)(cg0 + w * 64 + ct * 32 + l32) * DIM + h * 8;

    const int fa  = (l32 >> 1) & 3;
    const int pk0 = ((0 + h) ^ fa) * 16;     // ks=0 piece offset in swizzled row
    const int pk1 = ((2 + h) ^ fa) * 16;     // ks=1 piece offset
    const int ar0 = (0 * 32 + l32) * 64;     // rt=0 row byte offset
    const int ar1 = (1 * 32 + l32) * 64;     // rt=1

    float mp[2][16];
    #pragma unroll
    for (int rt = 0; rt < 2; rt++)
        #pragma unroll
        for (int r = 0; r < 16; r++) mp[rt][r] = -3.0e38f;

    __syncthreads();   // A staged; the ONLY barrier before the epilogue

    #pragma unroll
    for (int p = 0; p < PASSES; ++p) {
        f32x16 acc[2][2];
        #pragma unroll
        for (int rt = 0; rt < 2; rt++)
            #pragma unroll
            for (int ct = 0; ct < 2; ct++)
                #pragma unroll
                for (int r = 0; r < 16; r++) acc[rt][ct][r] = -hcv[p][ct];

        const ushort_t* bp0 = bbase[0] + (size_t)p * 256 * DIM;
        const ushort_t* bp1 = bbase[1] + (size_t)p * 256 * DIM;

        #pragma unroll
        for (int kc = 0; kc < 8; ++kc) {
            bf16x8 af[2][2], bfr[2][2];
            af[0][0] = *(const bf16x8*)(As[kc] + ar0 + pk0);
            af[0][1] = *(const bf16x8*)(As[kc] + ar0 + pk1);
            af[1][0] = *(const bf16x8*)(As[kc] + ar1 + pk0);
            af[1][1] = *(const bf16x8*)(As[kc] + ar1 + pk1);
            bfr[0][0] = *(const bf16x8*)(bp0 + kc * 32);
            bfr[0][1] = *(const bf16x8*)(bp0 + kc * 32 + 16);
            bfr[1][0] = *(const bf16x8*)(bp1 + kc * 32);
            bfr[1][1] = *(const bf16x8*)(bp1 + kc * 32 + 16);
            #pragma unroll
            for (int ks = 0; ks < 2; ks++)
                #pragma unroll
                for (int rt = 0; rt < 2; rt++)
                    #pragma unroll
                    for (int ct = 0; ct < 2; ct++)
                        acc[rt][ct] = __builtin_amdgcn_mfma_f32_32x32x16_bf16(
                            af[rt][ks], bfr[ct][ks], acc[rt][ct], 0, 0, 0);
        }

        // fold pass into running max (pack 11-bit code id into low mantissa bits)
        #pragma unroll
        for (int ct = 0; ct < 2; ct++) {
            const unsigned code = (unsigned)(cg0 + p * 256 + w * 64 + ct * 32 + l32);
            #pragma unroll
            for (int rt = 0; rt < 2; rt++)
                #pragma unroll
                for (int r = 0; r < 16; r++) {
                    unsigned u = (__float_as_uint(acc[rt][ct][r]) & 0xFFFFF800u) | code;
                    mp[rt][r] = fmaxf(mp[rt][r], __uint_as_float(u));
                }
        }
    }

    // ---- cross-lane argmax over the 32 lanes sharing each output row ----
    #pragma unroll
    for (int m = 1; m <= 16; m <<= 1)
        #pragma unroll
        for (int rt = 0; rt < 2; rt++)
            #pragma unroll
            for (int r = 0; r < 16; r++)
                mp[rt][r] = fmaxf(mp[rt][r], __shfl_xor(mp[rt][r], m, 64));

    if (l32 == 0) {
        #pragma unroll
        for (int rt = 0; rt < 2; rt++)
            #pragma unroll
            for (int r = 0; r < 16; r++) {
                const int row = rt * 32 + (r & 3) + 8 * (r >> 2) + 4 * h;
                red[row][w] = mp[rt][r];
            }
    }
    __syncthreads();
    if (t < 64) {
        float b0 = fmaxf(fmaxf(red[t][0], red[t][1]), fmaxf(red[t][2], red[t][3]));
        part[(size_t)(row0 + t) * CSPLIT + blockIdx.x] = b0;
    }
}

// ---------------- epilogue: reduce partials + gather + loss ---------------------
__global__ void finish_kernel(const float* __restrict__ x, const float* __restrict__ cb,
                              const float* __restrict__ part, float* __restrict__ out,
                              float* __restrict__ loss) {
    const int t = threadIdx.x;    // 256 threads cover D
    float lsum = 0.0f;
    #pragma unroll
    for (int r = 0; r < 16; r++) {
        const int row = blockIdx.x * 16 + r;
        float2 pr = *(const float2*)&part[(size_t)row * CSPLIT];
        float b = fmaxf(pr.x, pr.y);
        const int code = (int)(__float_as_uint(b) & 2047u);
        const float c  = cb[(size_t)code * DIM + t];
        const float xv = x[(size_t)row * DIM + t];
        out[(size_t)row * DIM + t] = c;
        const float diff = xv - c;
        lsum += diff * diff;
    }
    #pragma unroll
    for (int o = 32; o > 0; o >>= 1) lsum += __shfl_down(lsum, o, 64);
    __shared__ float red[4];
    if ((t & 63) == 0) red[t >> 6] = lsum;
    __syncthreads();
    if (t == 0) {
        const float scale = 1.25f / (float)((size_t)N_ROWS * DIM);  // (beta+1)/(N*D)
        atomicAdd(loss, (red[0] + red[1] + red[2] + red[3]) * scale);
    }
}

extern "C" void kernel_launch(void* const* d_in, const int* in_sizes, int n_in,
                              void* d_out, int out_size, void* d_ws, size_t ws_size,
                              hipStream_t stream) {
    const float* x  = (const float*)d_in[0];
    const float* cb = (const float*)d_in[1];
    float* out  = (float*)d_out;
    float* loss = out + (size_t)N_ROWS * DIM;

    char* ws = (char*)d_ws;
    ushort_t* cbb    = (ushort_t*)ws;                               // 1 MB
    float*    halfcn = (float*)(ws + (size_t)KCODES * DIM * 2);     // 8 KB
    float*    part   = (float*)(ws + (size_t)KCODES * DIM * 2 + KCODES * 4);  // 256 KB

    prep_cb<<<KCODES, 256, 0, stream>>>(cb, cbb, halfcn, loss);
    argmin_mfma<<<dim3(CSPLIT, N_ROWS / 64), 256, 0, stream>>>(x, cbb, halfcn, part);
    finish_kernel<<<N_ROWS / 16, 256, 0, stream>>>(x, cb, part, out, loss);
}

// Round 6
// 126.530 us; speedup vs baseline: 2.2704x; 1.5018x over previous
//
#include <hip/hip_runtime.h>

#define N_ROWS 32768
#define DIM    256
#define KCODES 2048
#define CSCALE 4096.0f

typedef unsigned short ushort_t;
typedef __attribute__((ext_vector_type(16))) float f32x16;

__device__ __forceinline__ void gl16(const void* g, void* l) {
    __builtin_amdgcn_global_load_lds(
        (const __attribute__((address_space(1))) unsigned int*)g,
        (__attribute__((address_space(3))) unsigned int*)l, 16, 0, 0);
}

// pack 16 fp32 -> 16 fp8 e4m3 (4 dwords)
__device__ __forceinline__ uint4 pack16(const float* s) {
    int a = __builtin_amdgcn_cvt_pk_fp8_f32(s[0],  s[1],  0, false);
    a     = __builtin_amdgcn_cvt_pk_fp8_f32(s[2],  s[3],  a, true);
    int b = __builtin_amdgcn_cvt_pk_fp8_f32(s[4],  s[5],  0, false);
    b     = __builtin_amdgcn_cvt_pk_fp8_f32(s[6],  s[7],  b, true);
    int c = __builtin_amdgcn_cvt_pk_fp8_f32(s[8],  s[9],  0, false);
    c     = __builtin_amdgcn_cvt_pk_fp8_f32(s[10], s[11], c, true);
    int d = __builtin_amdgcn_cvt_pk_fp8_f32(s[12], s[13], 0, false);
    d     = __builtin_amdgcn_cvt_pk_fp8_f32(s[14], s[15], d, true);
    uint4 o; o.x = a; o.y = b; o.z = c; o.w = d;
    return o;
}

// ---------------- prologue: cb -> fp8 (x4096), halfcn' = 4096*0.5*||c||^2 -------
__global__ void prep_cb(const float* __restrict__ cb, ushort_t* __restrict__ cbf8,
                        float* __restrict__ halfcn, float* __restrict__ loss) {
    const int code = blockIdx.x;
    const int t = threadIdx.x;               // 0..127, dim pairs
    if (code == 0 && t == 0) *loss = 0.0f;
    float2 v = *(const float2*)&cb[code * DIM + t * 2];
    int p = __builtin_amdgcn_cvt_pk_fp8_f32(v.x * CSCALE, v.y * CSCALE, 0, false);
    cbf8[code * 128 + t] = (ushort_t)p;
    float s = v.x * v.x + v.y * v.y;
    #pragma unroll
    for (int o = 32; o > 0; o >>= 1) s += __shfl_down(s, o, 64);
    __shared__ float red[2];
    if ((t & 63) == 0) red[t >> 6] = s;
    __syncthreads();
    if (t == 0) halfcn[code] = 0.5f * CSCALE * (red[0] + red[1]);
}

// ---------------- fused: argmin over all 2048 codes + gather + loss -------------
// score(n,k) = x_n . (4096 c_k) - 4096*0.5||c_k||^2, fp8 MFMA; argmax == argmin dist.
// A (64 rows x 256k fp8) persistent in LDS (converted in-block); B double-buffered
// via global_load_lds, BK=64 -> 16 MFMA/wave per barrier. Fused gather/loss epilogue.
__global__ __launch_bounds__(256, 3) void vq_fused(
        const float* __restrict__ x, const float* __restrict__ cb,
        const char* __restrict__ cbf8, const float* __restrict__ halfcn,
        float* __restrict__ out, float* __restrict__ loss) {
    __shared__ char As[4][4096];      // [kc][64 rows x 64B], 16B-granule XOR swizzle
    __shared__ char Bs[2][16384];     // 256 codes x 64B, swizzled
    __shared__ float red[64][4];
    __shared__ int  idxs[64];
    __shared__ float lred[4];

    const int t    = threadIdx.x;
    const int lane = t & 63;
    const int w    = t >> 6;          // wave -> 64-code quadrant within a 256 pass-tile
    const int l32  = lane & 31;
    const int h    = lane >> 5;
    const int row0 = blockIdx.x * 64;

    // ---- stage A once: fp32 -> fp8 e4m3, coalesced reads, swizzled LDS ----
    {
        const int r   = t >> 2;               // row 0..63
        const int kc  = t & 3;                // 64-k chunk
        const int key = (r >> 1) & 3;
        const float* src = x + (size_t)(row0 + r) * DIM + kc * 64;
        float buf[16];
        #pragma unroll
        for (int g = 0; g < 4; g++) {
            #pragma unroll
            for (int j = 0; j < 4; j++)
                *(float4*)(buf + j * 4) = *(const float4*)(src + g * 16 + j * 4);
            *(uint4*)(As[kc] + r * 64 + (g ^ key) * 16) = pack16(buf);
        }
    }

    // ---- B staging: 16 KB (256 codes x 64B) per iter, 4 gl_lds per thread ----
    auto stageB = [&](int pass, int kc, char* buf) {
        #pragma unroll
        for (int r_ = 0; r_ < 4; r_++) {
            const int lc = r_ * 64 + w * 16 + (lane >> 2);      // local code
            const int g  = (lane & 3) ^ ((lc >> 1) & 3);
            const char* src = cbf8 + (size_t)(pass * 256 + lc) * 256 + kc * 64 + g * 16;
            gl16(src, buf + (r_ * 64 + w * 16) * 64);           // wave-uniform base
        }
    };

    float mp[2][16];
    #pragma unroll
    for (int rt = 0; rt < 2; rt++)
        #pragma unroll
        for (int r = 0; r < 16; r++) mp[rt][r] = -3.0e38f;

    const int akey = (l32 >> 1) & 3;

    stageB(0, 0, Bs[0]);
    int cur = 0;
    for (int pass = 0; pass < 8; ++pass) {
        const float hc0 = halfcn[pass * 256 + w * 64 + l32];
        const float hc1 = halfcn[pass * 256 + w * 64 + 32 + l32];
        f32x16 acc[2][2];
        #pragma unroll
        for (int rt = 0; rt < 2; rt++)
            #pragma unroll
            for (int r = 0; r < 16; r++) { acc[rt][0][r] = -hc0; acc[rt][1][r] = -hc1; }

        #pragma unroll
        for (int kc = 0; kc < 4; ++kc) {
            __syncthreads();   // Bs[cur] staged (vmcnt drain); prior reads of other buf done
            const int i = pass * 4 + kc;
            if (i < 31) stageB((i + 1) >> 2, (i + 1) & 3, Bs[cur ^ 1]);

            const char* ab = As[kc];
            const char* bb = Bs[cur];
            long af[2][4], bf[2][4];
            #pragma unroll
            for (int rt = 0; rt < 2; rt++) {
                const int rbase = (rt * 32 + l32) * 64 + h * 8;
                #pragma unroll
                for (int ks = 0; ks < 4; ks++)
                    af[rt][ks] = *(const long*)(ab + rbase + ((ks ^ akey) * 16));
            }
            #pragma unroll
            for (int ct = 0; ct < 2; ct++) {
                const int lc = w * 64 + ct * 32 + l32;
                const int bkey = (lc >> 1) & 3;
                const int cbase = lc * 64 + h * 8;
                #pragma unroll
                for (int ks = 0; ks < 4; ks++)
                    bf[ct][ks] = *(const long*)(bb + cbase + ((ks ^ bkey) * 16));
            }
            #pragma unroll
            for (int ks = 0; ks < 4; ks++)
                #pragma unroll
                for (int rt = 0; rt < 2; rt++)
                    #pragma unroll
                    for (int ct = 0; ct < 2; ct++)
                        acc[rt][ct] = __builtin_amdgcn_mfma_f32_32x32x16_fp8_fp8(
                            af[rt][ks], bf[ct][ks], acc[rt][ct], 0, 0, 0);
            cur ^= 1;
        }

        // fold pass into running max (pack 11-bit code id into low mantissa bits)
        #pragma unroll
        for (int ct = 0; ct < 2; ct++) {
            const unsigned code = (unsigned)(pass * 256 + w * 64 + ct * 32 + l32);
            #pragma unroll
            for (int rt = 0; rt < 2; rt++)
                #pragma unroll
                for (int r = 0; r < 16; r++) {
                    unsigned u = (__float_as_uint(acc[rt][ct][r]) & 0xFFFFF800u) | code;
                    mp[rt][r] = fmaxf(mp[rt][r], __uint_as_float(u));
                }
        }
    }

    // ---- cross-lane argmax over the 32 lanes sharing each output row ----
    #pragma unroll
    for (int m = 1; m <= 16; m <<= 1)
        #pragma unroll
        for (int rt = 0; rt < 2; rt++)
            #pragma unroll
            for (int r = 0; r < 16; r++)
                mp[rt][r] = fmaxf(mp[rt][r], __shfl_xor(mp[rt][r], m, 64));

    if (l32 == 0) {
        #pragma unroll
        for (int rt = 0; rt < 2; rt++)
            #pragma unroll
            for (int r = 0; r < 16; r++) {
                const int row = rt * 32 + (r & 3) + 8 * (r >> 2) + 4 * h;
                red[row][w] = mp[rt][r];
            }
    }
    __syncthreads();
    if (t < 64) {
        float b0 = fmaxf(fmaxf(red[t][0], red[t][1]), fmaxf(red[t][2], red[t][3]));
        idxs[t] = (int)(__float_as_uint(b0) & 2047u);
    }
    __syncthreads();

    // ---- fused gather (fp32 codebook) + loss partial ----
    float lsum = 0.0f;
    #pragma unroll 4
    for (int r = 0; r < 64; r++) {
        const int code = idxs[r];
        const float c  = cb[(size_t)code * DIM + t];
        const float xv = x[(size_t)(row0 + r) * DIM + t];
        out[(size_t)(row0 + r) * DIM + t] = c;
        const float d = xv - c;
        lsum += d * d;
    }
    #pragma unroll
    for (int o = 32; o > 0; o >>= 1) lsum += __shfl_down(lsum, o, 64);
    if ((lane) == 0) lred[w] = lsum;
    __syncthreads();
    if (t == 0) {
        const float scale = 1.25f / (float)((size_t)N_ROWS * DIM);  // (beta+1)/(N*D)
        atomicAdd(loss, (lred[0] + lred[1] + lred[2] + lred[3]) * scale);
    }
}

extern "C" void kernel_launch(void* const* d_in, const int* in_sizes, int n_in,
                              void* d_out, int out_size, void* d_ws, size_t ws_size,
                              hipStream_t stream) {
    const float* x  = (const float*)d_in[0];
    const float* cb = (const float*)d_in[1];
    float* out  = (float*)d_out;
    float* loss = out + (size_t)N_ROWS * DIM;

    char* ws = (char*)d_ws;
    ushort_t* cbf8   = (ushort_t*)ws;                              // 512 KB
    float*    halfcn = (float*)(ws + (size_t)KCODES * 128 * 2);    // 8 KB

    prep_cb<<<KCODES, 128, 0, stream>>>(cb, cbf8, halfcn, loss);
    vq_fused<<<N_ROWS / 64, 256, 0, stream>>>(x, cb, (const char*)cbf8, halfcn, out, loss);
}

// Round 7
// 126.010 us; speedup vs baseline: 2.2798x; 1.0041x over previous
//
#include <hip/hip_runtime.h>

#define N_ROWS 32768
#define DIM    256
#define KCODES 2048
#define CSCALE 4096.0f

typedef __attribute__((ext_vector_type(16))) float f32x16;
typedef __attribute__((ext_vector_type(4)))  unsigned int u32x4;

union frag16 { u32x4 v; long l[2]; };

__device__ __forceinline__ void gl16(const void* g, void* l) {
    __builtin_amdgcn_global_load_lds(
        (const __attribute__((address_space(1))) unsigned int*)g,
        (__attribute__((address_space(3))) unsigned int*)l, 16, 0, 0);
}

// pack 16 fp32 -> 16 fp8 e4m3 (4 dwords)
__device__ __forceinline__ uint4 pack16(const float* s) {
    int a = __builtin_amdgcn_cvt_pk_fp8_f32(s[0],  s[1],  0, false);
    a     = __builtin_amdgcn_cvt_pk_fp8_f32(s[2],  s[3],  a, true);
    int b = __builtin_amdgcn_cvt_pk_fp8_f32(s[4],  s[5],  0, false);
    b     = __builtin_amdgcn_cvt_pk_fp8_f32(s[6],  s[7],  b, true);
    int c = __builtin_amdgcn_cvt_pk_fp8_f32(s[8],  s[9],  0, false);
    c     = __builtin_amdgcn_cvt_pk_fp8_f32(s[10], s[11], c, true);
    int d = __builtin_amdgcn_cvt_pk_fp8_f32(s[12], s[13], 0, false);
    d     = __builtin_amdgcn_cvt_pk_fp8_f32(s[14], s[15], d, true);
    uint4 o; o.x = a; o.y = b; o.z = c; o.w = d;
    return o;
}

// Piece layout: within each 64B k-chunk, piece d (=h*2+q, 16B) holds the two 8B
// MFMA fragments (ks=2q, ks=2q+1) for k-half h:
//   piece bytes [0,8)  = k = q*32      + h*8 + [0,8)
//   piece bytes [8,16) = k = q*32 + 16 + h*8 + [0,8)

// ---------------- prologue: cb -> fp8 (x4096) in piece layout + halfcn ----------
__global__ void prep_cb(const float* __restrict__ cb, unsigned int* __restrict__ cbf8,
                        float* __restrict__ halfcn, float* __restrict__ loss) {
    const int t    = threadIdx.x;            // 256 thr = 4 codes x 64 dword slots
    const int code = blockIdx.x * 4 + (t >> 6);
    const int s    = t & 63;                 // output dword slot
    if (blockIdx.x == 0 && t == 0) *loss = 0.0f;
    const int kc = s >> 4, d = (s >> 2) & 3, b4 = (s & 3) * 4;
    const int h = d >> 1, q = d & 1;
    const int k0 = kc * 64 + q * 32 + (b4 >> 3) * 16 + h * 8 + (b4 & 7);
    float4 v = *(const float4*)&cb[(size_t)code * DIM + k0];
    int pk = __builtin_amdgcn_cvt_pk_fp8_f32(v.x * CSCALE, v.y * CSCALE, 0, false);
    pk     = __builtin_amdgcn_cvt_pk_fp8_f32(v.z * CSCALE, v.w * CSCALE, pk, true);
    cbf8[(size_t)code * 64 + s] = (unsigned int)pk;
    float ssum = v.x * v.x + v.y * v.y + v.z * v.z + v.w * v.w;  // all 256 covered once
    #pragma unroll
    for (int o = 32; o > 0; o >>= 1) ssum += __shfl_down(ssum, o, 64);
    if (s == 0) halfcn[code] = 0.5f * CSCALE * ssum;
}

// ---------------- fused: argmin over all 2048 codes + gather + loss -------------
// score(n,k) = x_n . (4096 c_k) - 4096*0.5||c_k||^2, fp8 MFMA; argmax == argmin dist.
// A persistent in LDS (piece-packed during fp32->fp8 convert); B double-buffered
// via global_load_lds from the piece-layout fp8 codebook. All fragment reads are
// conflict-free ds_read_b128 (8 starts x 4-bank span tile 32 banks at 4 dw/bank).
__global__ __launch_bounds__(256, 3) void vq_fused(
        const float* __restrict__ x, const float* __restrict__ cb,
        const char* __restrict__ cbf8, const float* __restrict__ halfcn,
        float* __restrict__ out, float* __restrict__ loss) {
    __shared__ char As[4][4096];      // [kc][64 rows x 64B], 16B-granule XOR swizzle
    __shared__ char Bs[2][16384];     // 256 codes x 64B, swizzled
    __shared__ float red[64][4];
    __shared__ int  idxs[64];
    __shared__ float lred[4];

    const int t    = threadIdx.x;
    const int lane = t & 63;
    const int w    = t >> 6;          // wave -> 64-code quadrant within a 256 pass-tile
    const int l32  = lane & 31;
    const int h    = lane >> 5;
    const int row0 = blockIdx.x * 64;

    // ---- stage A once: fp32 -> fp8 e4m3 pieces, swizzled LDS ----
    {
        const int r   = t >> 2;               // row 0..63
        const int kc  = t & 3;                // 64-k chunk
        const int key = (r >> 1) & 3;
        const float* src = x + (size_t)(row0 + r) * DIM + kc * 64;
        float buf[16];
        #pragma unroll
        for (int p = 0; p < 4; p++) {
            const int d = p ^ key, hh = d >> 1, qq = d & 1;
            #pragma unroll
            for (int j = 0; j < 4; j++) *(float4*)(buf + j * 4) =
                *(const float4*)(src + qq * 32 + (j >> 1) * 16 + hh * 8 + (j & 1) * 4);
            *(uint4*)(As[kc] + r * 64 + p * 16) = pack16(buf);
        }
    }

    // ---- B staging: 16 KB (256 codes x 64B) per iter, 4 gl_lds per thread ----
    auto stageB = [&](int pass, int kc, char* buf) {
        #pragma unroll
        for (int r_ = 0; r_ < 4; r_++) {
            const int lc = r_ * 64 + w * 16 + (lane >> 2);      // local code
            const int g  = (lane & 3) ^ ((lc >> 1) & 3);        // content piece idx
            const char* src = cbf8 + (size_t)(pass * 256 + lc) * 256 + kc * 64 + g * 16;
            gl16(src, buf + (r_ * 64 + w * 16) * 64);           // wave-uniform base
        }
    };

    float mp[2][16];
    #pragma unroll
    for (int rt = 0; rt < 2; rt++)
        #pragma unroll
        for (int r = 0; r < 16; r++) mp[rt][r] = -3.0e38f;

    const int key = (l32 >> 1) & 3;           // same for A rows and B rows
    const int p0  = (h * 2 + 0) ^ key;        // piece position for q=0
    const int p1  = (h * 2 + 1) ^ key;        // piece position for q=1

    stageB(0, 0, Bs[0]);
    int cur = 0;
    for (int pass = 0; pass < 8; ++pass) {
        const float hc0 = halfcn[pass * 256 + w * 64 + l32];
        const float hc1 = halfcn[pass * 256 + w * 64 + 32 + l32];
        f32x16 acc[2][2];
        #pragma unroll
        for (int rt = 0; rt < 2; rt++)
            #pragma unroll
            for (int r = 0; r < 16; r++) { acc[rt][0][r] = -hc0; acc[rt][1][r] = -hc1; }

        #pragma unroll
        for (int kc = 0; kc < 4; ++kc) {
            __syncthreads();   // Bs[cur] staged (vmcnt drain); prior reads of other buf done
            const int i = pass * 4 + kc;
            if (i < 31) stageB((i + 1) >> 2, (i + 1) & 3, Bs[cur ^ 1]);

            const char* ab = As[kc];
            const char* bb = Bs[cur];
            frag16 af[2][2], bf[2][2];
            #pragma unroll
            for (int rt = 0; rt < 2; rt++) {
                const int rbase = (rt * 32 + l32) * 64;
                af[rt][0].v = *(const u32x4*)(ab + rbase + p0 * 16);
                af[rt][1].v = *(const u32x4*)(ab + rbase + p1 * 16);
            }
            #pragma unroll
            for (int ct = 0; ct < 2; ct++) {
                const int cbase = (w * 64 + ct * 32 + l32) * 64;
                bf[ct][0].v = *(const u32x4*)(bb + cbase + p0 * 16);
                bf[ct][1].v = *(const u32x4*)(bb + cbase + p1 * 16);
            }
            #pragma unroll
            for (int q = 0; q < 2; q++)
                #pragma unroll
                for (int hf = 0; hf < 2; hf++)
                    #pragma unroll
                    for (int rt = 0; rt < 2; rt++)
                        #pragma unroll
                        for (int ct = 0; ct < 2; ct++)
                            acc[rt][ct] = __builtin_amdgcn_mfma_f32_32x32x16_fp8_fp8(
                                af[rt][q].l[hf], bf[ct][q].l[hf], acc[rt][ct], 0, 0, 0);
            cur ^= 1;
        }

        // fold pass into running max (pack 11-bit code id into low mantissa bits)
        #pragma unroll
        for (int ct = 0; ct < 2; ct++) {
            const unsigned code = (unsigned)(pass * 256 + w * 64 + ct * 32 + l32);
            #pragma unroll
            for (int rt = 0; rt < 2; rt++)
                #pragma unroll
                for (int r = 0; r < 16; r++) {
                    unsigned u = (__float_as_uint(acc[rt][ct][r]) & 0xFFFFF800u) | code;
                    mp[rt][r] = fmaxf(mp[rt][r], __uint_as_float(u));
                }
        }
    }

    // ---- cross-lane argmax over the 32 lanes sharing each output row ----
    #pragma unroll
    for (int m = 1; m <= 16; m <<= 1)
        #pragma unroll
        for (int rt = 0; rt < 2; rt++)
            #pragma unroll
            for (int r = 0; r < 16; r++)
                mp[rt][r] = fmaxf(mp[rt][r], __shfl_xor(mp[rt][r], m, 64));

    if (l32 == 0) {
        #pragma unroll
        for (int rt = 0; rt < 2; rt++)
            #pragma unroll
            for (int r = 0; r < 16; r++) {
                const int row = rt * 32 + (r & 3) + 8 * (r >> 2) + 4 * h;
                red[row][w] = mp[rt][r];
            }
    }
    __syncthreads();
    if (t < 64) {
        float b0 = fmaxf(fmaxf(red[t][0], red[t][1]), fmaxf(red[t][2], red[t][3]));
        idxs[t] = (int)(__float_as_uint(b0) & 2047u);
    }
    __syncthreads();

    // ---- fused gather (fp32 codebook) + loss partial ----
    float lsum = 0.0f;
    #pragma unroll 4
    for (int r = 0; r < 64; r++) {
        const int code = idxs[r];
        const float c  = cb[(size_t)code * DIM + t];
        const float xv = x[(size_t)(row0 + r) * DIM + t];
        out[(size_t)(row0 + r) * DIM + t] = c;
        const float d = xv - c;
        lsum += d * d;
    }
    #pragma unroll
    for (int o = 32; o > 0; o >>= 1) lsum += __shfl_down(lsum, o, 64);
    if (lane == 0) lred[w] = lsum;
    __syncthreads();
    if (t == 0) {
        const float scale = 1.25f / (float)((size_t)N_ROWS * DIM);  // (beta+1)/(N*D)
        atomicAdd(loss, (lred[0] + lred[1] + lred[2] + lred[3]) * scale);
    }
}

extern "C" void kernel_launch(void* const* d_in, const int* in_sizes, int n_in,
                              void* d_out, int out_size, void* d_ws, size_t ws_size,
                              hipStream_t stream) {
    const float* x  = (const float*)d_in[0];
    const float* cb = (const float*)d_in[1];
    float* out  = (float*)d_out;
    float* loss = out + (size_t)N_ROWS * DIM;

    char* ws = (char*)d_ws;
    unsigned int* cbf8 = (unsigned int*)ws;                        // 512 KB
    float* halfcn = (float*)(ws + (size_t)KCODES * 256);           // 8 KB

    prep_cb<<<KCODES / 4, 256, 0, stream>>>(cb, cbf8, halfcn, loss);
    vq_fused<<<N_ROWS / 64, 256, 0, stream>>>(x, cb, (const char*)cbf8, halfcn, out, loss);
}

// Round 8
// 123.449 us; speedup vs baseline: 2.3271x; 1.0207x over previous
//
#include <hip/hip_runtime.h>

#define N_ROWS 32768
#define DIM    256
#define KCODES 2048
#define CSCALE 4096.0f

typedef __attribute__((ext_vector_type(16))) float f32x16;
typedef __attribute__((ext_vector_type(4)))  unsigned int u32x4;

union frag16 { u32x4 v; long l[2]; };

// s_waitcnt immediates (gfx9/CDNA encoding: vmcnt[3:0]+[15:14], expcnt[6:4], lgkmcnt[11:8])
#define WAIT_LGKM0 0xC07F   // lgkmcnt(0), vmcnt/expcnt = no-wait
#define WAIT_VM4   0x0F74   // vmcnt(4),  lgkmcnt/expcnt = no-wait
#define WAIT_VM0   0x0F70   // vmcnt(0),  lgkmcnt/expcnt = no-wait

__device__ __forceinline__ void gl16(const void* g, void* l) {
    __builtin_amdgcn_global_load_lds(
        (const __attribute__((address_space(1))) unsigned int*)g,
        (__attribute__((address_space(3))) unsigned int*)l, 16, 0, 0);
}

// pack 16 fp32 -> 16 fp8 e4m3 (4 dwords)
__device__ __forceinline__ uint4 pack16(const float* s) {
    int a = __builtin_amdgcn_cvt_pk_fp8_f32(s[0],  s[1],  0, false);
    a     = __builtin_amdgcn_cvt_pk_fp8_f32(s[2],  s[3],  a, true);
    int b = __builtin_amdgcn_cvt_pk_fp8_f32(s[4],  s[5],  0, false);
    b     = __builtin_amdgcn_cvt_pk_fp8_f32(s[6],  s[7],  b, true);
    int c = __builtin_amdgcn_cvt_pk_fp8_f32(s[8],  s[9],  0, false);
    c     = __builtin_amdgcn_cvt_pk_fp8_f32(s[10], s[11], c, true);
    int d = __builtin_amdgcn_cvt_pk_fp8_f32(s[12], s[13], 0, false);
    d     = __builtin_amdgcn_cvt_pk_fp8_f32(s[14], s[15], d, true);
    uint4 o; o.x = a; o.y = b; o.z = c; o.w = d;
    return o;
}

// Piece layout: within each 64B k-chunk, piece d (=h*2+q, 16B) holds the two 8B
// MFMA fragments (ks=2q, ks=2q+1) for k-half h:
//   piece bytes [0,8)  = k = q*32      + h*8 + [0,8)
//   piece bytes [8,16) = k = q*32 + 16 + h*8 + [0,8)

// ---------------- prologue: cb -> fp8 (x4096) in piece layout + halfcn ----------
__global__ void prep_cb(const float* __restrict__ cb, unsigned int* __restrict__ cbf8,
                        float* __restrict__ halfcn, float* __restrict__ loss) {
    const int t    = threadIdx.x;            // 256 thr = 4 codes x 64 dword slots
    const int code = blockIdx.x * 4 + (t >> 6);
    const int s    = t & 63;                 // output dword slot
    if (blockIdx.x == 0 && t == 0) *loss = 0.0f;
    const int kc = s >> 4, d = (s >> 2) & 3, b4 = (s & 3) * 4;
    const int h = d >> 1, q = d & 1;
    const int k0 = kc * 64 + q * 32 + (b4 >> 3) * 16 + h * 8 + (b4 & 7);
    float4 v = *(const float4*)&cb[(size_t)code * DIM + k0];
    int pk = __builtin_amdgcn_cvt_pk_fp8_f32(v.x * CSCALE, v.y * CSCALE, 0, false);
    pk     = __builtin_amdgcn_cvt_pk_fp8_f32(v.z * CSCALE, v.w * CSCALE, pk, true);
    cbf8[(size_t)code * 64 + s] = (unsigned int)pk;
    float ssum = v.x * v.x + v.y * v.y + v.z * v.z + v.w * v.w;  // all 256 covered once
    #pragma unroll
    for (int o = 32; o > 0; o >>= 1) ssum += __shfl_down(ssum, o, 64);
    if (s == 0) halfcn[code] = 0.5f * CSCALE * ssum;
}

// ---------------- fused: argmin over all 2048 codes + gather + loss -------------
// score(n,k) = x_n . (4096 c_k) - 4096*0.5||c_k||^2, fp8 MFMA; argmax == argmin dist.
// BARRIER-FREE K-loop: each wave stages its own 64 codes into a wave-private LDS
// ring buffer (2 x 4 KB) via global_load_lds and self-syncs with s_waitcnt
// vmcnt(4) (next stage stays in flight) + lgkmcnt(0) overwrite guard. A persistent
// shared LDS (one barrier after staging). Fused gather/loss epilogue.
__global__ __launch_bounds__(256, 2) void vq_fused(
        const float* __restrict__ x, const float* __restrict__ cb,
        const char* __restrict__ cbf8, const float* __restrict__ halfcn,
        float* __restrict__ out, float* __restrict__ loss) {
    __shared__ char As[4][4096];      // [kc][64 rows x 64B], 16B-granule XOR swizzle
    __shared__ char Bs[2][4][4096];   // [ring][wave][64 codes x 64B], swizzled
    __shared__ float red[64][4];
    __shared__ int  idxs[64];
    __shared__ float lred[4];

    const int t    = threadIdx.x;
    const int lane = t & 63;
    const int w    = t >> 6;          // wave -> 64-code group within each 256 pass-tile
    const int l32  = lane & 31;
    const int h    = lane >> 5;
    const int row0 = blockIdx.x * 64;

    // ---- stage A once: fp32 -> fp8 e4m3 pieces, swizzled LDS ----
    {
        const int r   = t >> 2;               // row 0..63
        const int kc  = t & 3;                // 64-k chunk
        const int key = (r >> 1) & 3;
        const float* src = x + (size_t)(row0 + r) * DIM + kc * 64;
        float buf[16];
        #pragma unroll
        for (int p = 0; p < 4; p++) {
            const int d = p ^ key, hh = d >> 1, qq = d & 1;
            #pragma unroll
            for (int j = 0; j < 4; j++) *(float4*)(buf + j * 4) =
                *(const float4*)(src + qq * 32 + (j >> 1) * 16 + hh * 8 + (j & 1) * 4);
            *(uint4*)(As[kc] + r * 64 + p * 16) = pack16(buf);
        }
    }

    // ---- bias preload: 0.5||c||^2 for this wave's codes across all 8 passes ----
    float hcv[8][2];
    #pragma unroll
    for (int p = 0; p < 8; p++) {
        hcv[p][0] = halfcn[p * 256 + w * 64 + l32];
        hcv[p][1] = halfcn[p * 256 + w * 64 + 32 + l32];
    }

    // ---- wave-private B staging: 4 KB (this wave's 64 codes x 64B) per step ----
    // step i = pass*4 + kc; ring slot = i & 1; no cross-wave deps.
    const int lsub = lane >> 2;               // code sub-index 0..15 per gl16
    const int lpos = lane & 3;                // LDS piece position this lane fills
    auto stageB = [&](int i) {
        const int pass = i >> 2, kc = i & 3;
        char* dst = Bs[i & 1][w];
        #pragma unroll
        for (int r_ = 0; r_ < 4; r_++) {
            const int lc = r_ * 16 + lsub;                       // code within wave's 64
            const int g  = lpos ^ ((lc >> 1) & 3);               // content piece idx
            const char* src = cbf8 + (size_t)(pass * 256 + w * 64 + lc) * 256
                              + kc * 64 + g * 16;
            gl16(src, dst + r_ * 1024);                          // wave-uniform base
        }
    };

    float mp[2][16];
    #pragma unroll
    for (int rt = 0; rt < 2; rt++)
        #pragma unroll
        for (int r = 0; r < 16; r++) mp[rt][r] = -3.0e38f;

    const int key = (l32 >> 1) & 3;
    const int p0  = (h * 2 + 0) ^ key;        // piece position for q=0
    const int p1  = (h * 2 + 1) ^ key;        // piece position for q=1

    __syncthreads();                          // A visible to all waves
    stageB(0);

    for (int pass = 0; pass < 8; ++pass) {
        f32x16 acc[2][2];
        #pragma unroll
        for (int rt = 0; rt < 2; rt++)
            #pragma unroll
            for (int r = 0; r < 16; r++) {
                acc[rt][0][r] = -hcv[pass][0];
                acc[rt][1][r] = -hcv[pass][1];
            }

        #pragma unroll
        for (int kc = 0; kc < 4; ++kc) {
            const int i = pass * 4 + kc;
            // overwrite guard: prior step's ds_reads have landed in VGPRs
            __builtin_amdgcn_s_waitcnt(WAIT_LGKM0);
            if (i < 31) {
                stageB(i + 1);
                __builtin_amdgcn_s_waitcnt(WAIT_VM4);   // buf[i&1] staged; next in flight
            } else {
                __builtin_amdgcn_s_waitcnt(WAIT_VM0);
            }

            const char* ab = As[kc];
            const char* bb = Bs[i & 1][w];
            frag16 af[2][2], bf[2][2];
            #pragma unroll
            for (int rt = 0; rt < 2; rt++) {
                const int rbase = (rt * 32 + l32) * 64;
                af[rt][0].v = *(const u32x4*)(ab + rbase + p0 * 16);
                af[rt][1].v = *(const u32x4*)(ab + rbase + p1 * 16);
            }
            #pragma unroll
            for (int ct = 0; ct < 2; ct++) {
                const int cbase = (ct * 32 + l32) * 64;
                bf[ct][0].v = *(const u32x4*)(bb + cbase + p0 * 16);
                bf[ct][1].v = *(const u32x4*)(bb + cbase + p1 * 16);
            }
            #pragma unroll
            for (int q = 0; q < 2; q++)
                #pragma unroll
                for (int hf = 0; hf < 2; hf++)
                    #pragma unroll
                    for (int rt = 0; rt < 2; rt++)
                        #pragma unroll
                        for (int ct = 0; ct < 2; ct++)
                            acc[rt][ct] = __builtin_amdgcn_mfma_f32_32x32x16_fp8_fp8(
                                af[rt][q].l[hf], bf[ct][q].l[hf], acc[rt][ct], 0, 0, 0);
        }

        // fold pass into running max (pack 11-bit code id into low mantissa bits)
        #pragma unroll
        for (int ct = 0; ct < 2; ct++) {
            const unsigned code = (unsigned)(pass * 256 + w * 64 + ct * 32 + l32);
            #pragma unroll
            for (int rt = 0; rt < 2; rt++)
                #pragma unroll
                for (int r = 0; r < 16; r++) {
                    unsigned u = (__float_as_uint(acc[rt][ct][r]) & 0xFFFFF800u) | code;
                    mp[rt][r] = fmaxf(mp[rt][r], __uint_as_float(u));
                }
        }
    }

    // ---- cross-lane argmax over the 32 lanes sharing each output row ----
    #pragma unroll
    for (int m = 1; m <= 16; m <<= 1)
        #pragma unroll
        for (int rt = 0; rt < 2; rt++)
            #pragma unroll
            for (int r = 0; r < 16; r++)
                mp[rt][r] = fmaxf(mp[rt][r], __shfl_xor(mp[rt][r], m, 64));

    if (l32 == 0) {
        #pragma unroll
        for (int rt = 0; rt < 2; rt++)
            #pragma unroll
            for (int r = 0; r < 16; r++) {
                const int row = rt * 32 + (r & 3) + 8 * (r >> 2) + 4 * h;
                red[row][w] = mp[rt][r];
            }
    }
    __syncthreads();
    if (t < 64) {
        float b0 = fmaxf(fmaxf(red[t][0], red[t][1]), fmaxf(red[t][2], red[t][3]));
        idxs[t] = (int)(__float_as_uint(b0) & 2047u);
    }
    __syncthreads();

    // ---- fused gather (fp32 codebook) + loss partial ----
    float lsum = 0.0f;
    #pragma unroll 4
    for (int r = 0; r < 64; r++) {
        const int code = idxs[r];
        const float c  = cb[(size_t)code * DIM + t];
        const float xv = x[(size_t)(row0 + r) * DIM + t];
        out[(size_t)(row0 + r) * DIM + t] = c;
        const float d = xv - c;
        lsum += d * d;
    }
    #pragma unroll
    for (int o = 32; o > 0; o >>= 1) lsum += __shfl_down(lsum, o, 64);
    if (lane == 0) lred[w] = lsum;
    __syncthreads();
    if (t == 0) {
        const float scale = 1.25f / (float)((size_t)N_ROWS * DIM);  // (beta+1)/(N*D)
        atomicAdd(loss, (lred[0] + lred[1] + lred[2] + lred[3]) * scale);
    }
}

extern "C" void kernel_launch(void* const* d_in, const int* in_sizes, int n_in,
                              void* d_out, int out_size, void* d_ws, size_t ws_size,
                              hipStream_t stream) {
    const float* x  = (const float*)d_in[0];
    const float* cb = (const float*)d_in[1];
    float* out  = (float*)d_out;
    float* loss = out + (size_t)N_ROWS * DIM;

    char* ws = (char*)d_ws;
    unsigned int* cbf8 = (unsigned int*)ws;                        // 512 KB
    float* halfcn = (float*)(ws + (size_t)KCODES * 256);           // 8 KB

    prep_cb<<<KCODES / 4, 256, 0, stream>>>(cb, cbf8, halfcn, loss);
    vq_fused<<<N_ROWS / 64, 256, 0, stream>>>(x, cb, (const char*)cbf8, halfcn, out, loss);
}

// Round 9
// 121.994 us; speedup vs baseline: 2.3549x; 1.0119x over previous
//
#include <hip/hip_runtime.h>

#define N_ROWS 32768
#define DIM    256
#define KCODES 2048
#define CSCALE 4096.0f

typedef __attribute__((ext_vector_type(16))) float f32x16;
typedef __attribute__((ext_vector_type(4)))  unsigned int u32x4;

union frag16 { u32x4 v; long l[2]; };

// s_waitcnt immediates (gfx9/CDNA encoding: vmcnt[3:0]+[15:14], expcnt[6:4], lgkmcnt[11:8])
#define WAIT_LGKM0 0xC07F   // lgkmcnt(0), vmcnt/expcnt = no-wait
#define WAIT_VM4   0x0F74   // vmcnt(4),  lgkmcnt/expcnt = no-wait
#define WAIT_VM0   0x0F70   // vmcnt(0),  lgkmcnt/expcnt = no-wait

__device__ __forceinline__ void gl16(const void* g, void* l) {
    __builtin_amdgcn_global_load_lds(
        (const __attribute__((address_space(1))) unsigned int*)g,
        (__attribute__((address_space(3))) unsigned int*)l, 16, 0, 0);
}

// pack 16 fp32 -> 16 fp8 e4m3 (4 dwords)
__device__ __forceinline__ uint4 pack16(const float* s) {
    int a = __builtin_amdgcn_cvt_pk_fp8_f32(s[0],  s[1],  0, false);
    a     = __builtin_amdgcn_cvt_pk_fp8_f32(s[2],  s[3],  a, true);
    int b = __builtin_amdgcn_cvt_pk_fp8_f32(s[4],  s[5],  0, false);
    b     = __builtin_amdgcn_cvt_pk_fp8_f32(s[6],  s[7],  b, true);
    int c = __builtin_amdgcn_cvt_pk_fp8_f32(s[8],  s[9],  0, false);
    c     = __builtin_amdgcn_cvt_pk_fp8_f32(s[10], s[11], c, true);
    int d = __builtin_amdgcn_cvt_pk_fp8_f32(s[12], s[13], 0, false);
    d     = __builtin_amdgcn_cvt_pk_fp8_f32(s[14], s[15], d, true);
    uint4 o; o.x = a; o.y = b; o.z = c; o.w = d;
    return o;
}

// Piece layout: within each 64B k-chunk, piece d (=h*2+q, 16B) holds the two 8B
// MFMA fragments (ks=2q, ks=2q+1) for k-half h.

// ---------------- prologue: cb -> fp8 (x4096) in piece layout + halfcn ----------
__global__ void prep_cb(const float* __restrict__ cb, unsigned int* __restrict__ cbf8,
                        float* __restrict__ halfcn, float* __restrict__ loss) {
    const int t    = threadIdx.x;            // 256 thr = 4 codes x 64 dword slots
    const int code = blockIdx.x * 4 + (t >> 6);
    const int s    = t & 63;                 // output dword slot
    if (blockIdx.x == 0 && t == 0) *loss = 0.0f;
    const int kc = s >> 4, d = (s >> 2) & 3, b4 = (s & 3) * 4;
    const int h = d >> 1, q = d & 1;
    const int k0 = kc * 64 + q * 32 + (b4 >> 3) * 16 + h * 8 + (b4 & 7);
    float4 v = *(const float4*)&cb[(size_t)code * DIM + k0];
    int pk = __builtin_amdgcn_cvt_pk_fp8_f32(v.x * CSCALE, v.y * CSCALE, 0, false);
    pk     = __builtin_amdgcn_cvt_pk_fp8_f32(v.z * CSCALE, v.w * CSCALE, pk, true);
    cbf8[(size_t)code * 64 + s] = (unsigned int)pk;
    float ssum = v.x * v.x + v.y * v.y + v.z * v.z + v.w * v.w;
    #pragma unroll
    for (int o = 32; o > 0; o >>= 1) ssum += __shfl_down(ssum, o, 64);
    if (s == 0) halfcn[code] = 0.5f * CSCALE * ssum;
}

// ---------------- fused: argmin over all 2048 codes + gather + loss -------------
// Barrier-free K-loop + REGISTER double-buffered fragments: ds_reads for step i+1
// are issued BEFORE step i's MFMAs, so the ~220cyc LDS latency is hidden behind
// the 512cyc MFMA burst. Wave-private B ring in LDS via global_load_lds.
__global__ __launch_bounds__(256, 2) void vq_fused(
        const float* __restrict__ x, const float* __restrict__ cb,
        const char* __restrict__ cbf8, const float* __restrict__ halfcn,
        float* __restrict__ out, float* __restrict__ loss) {
    __shared__ char As[4][4096];      // [kc][64 rows x 64B], 16B-granule XOR swizzle
    __shared__ char Bs[2][4][4096];   // [ring][wave][64 codes x 64B], swizzled
    __shared__ float red[64][4];
    __shared__ int  idxs[64];
    __shared__ float lred[4];

    const int t    = threadIdx.x;
    const int lane = t & 63;
    const int w    = t >> 6;
    const int l32  = lane & 31;
    const int h    = lane >> 5;
    const int row0 = blockIdx.x * 64;

    // ---- stage A once: fp32 -> fp8 e4m3 pieces, swizzled LDS ----
    {
        const int r   = t >> 2;
        const int kc  = t & 3;
        const int key = (r >> 1) & 3;
        const float* src = x + (size_t)(row0 + r) * DIM + kc * 64;
        float buf[16];
        #pragma unroll
        for (int p = 0; p < 4; p++) {
            const int d = p ^ key, hh = d >> 1, qq = d & 1;
            #pragma unroll
            for (int j = 0; j < 4; j++) *(float4*)(buf + j * 4) =
                *(const float4*)(src + qq * 32 + (j >> 1) * 16 + hh * 8 + (j & 1) * 4);
            *(uint4*)(As[kc] + r * 64 + p * 16) = pack16(buf);
        }
    }

    // ---- bias preload ----
    float hcv[8][2];
    #pragma unroll
    for (int p = 0; p < 8; p++) {
        hcv[p][0] = halfcn[p * 256 + w * 64 + l32];
        hcv[p][1] = halfcn[p * 256 + w * 64 + 32 + l32];
    }

    // ---- wave-private B staging ----
    const int lsub = lane >> 2;
    const int lpos = lane & 3;
    auto stageB = [&](int i) {
        const int pass = i >> 2, kc = i & 3;
        char* dst = Bs[i & 1][w];
        #pragma unroll
        for (int r_ = 0; r_ < 4; r_++) {
            const int lc = r_ * 16 + lsub;
            const int g  = lpos ^ ((lc >> 1) & 3);
            const char* src = cbf8 + (size_t)(pass * 256 + w * 64 + lc) * 256
                              + kc * 64 + g * 16;
            gl16(src, dst + r_ * 1024);
        }
    };

    const int key = (l32 >> 1) & 3;
    const int p0  = (h * 2 + 0) ^ key;
    const int p1  = (h * 2 + 1) ^ key;

    frag16 af[2][2][2], bf[2][2][2];   // [set][rt|ct][q] — set index always literal

    float mp[2][16];
    #pragma unroll
    for (int rt = 0; rt < 2; rt++)
        #pragma unroll
        for (int r = 0; r < 16; r++) mp[rt][r] = -3.0e38f;

    __syncthreads();                  // A visible to all waves

    stageB(0);
    stageB(1);
    __builtin_amdgcn_s_waitcnt(WAIT_VM4);        // stage(0) complete
    // frags for step 0 -> set 0
    {
        const char* ab = As[0];
        const char* bb = Bs[0][w];
        #pragma unroll
        for (int rt = 0; rt < 2; rt++) {
            const int rbase = (rt * 32 + l32) * 64;
            af[0][rt][0].v = *(const u32x4*)(ab + rbase + p0 * 16);
            af[0][rt][1].v = *(const u32x4*)(ab + rbase + p1 * 16);
        }
        #pragma unroll
        for (int ct = 0; ct < 2; ct++) {
            const int cbase = (ct * 32 + l32) * 64;
            bf[0][ct][0].v = *(const u32x4*)(bb + cbase + p0 * 16);
            bf[0][ct][1].v = *(const u32x4*)(bb + cbase + p1 * 16);
        }
    }

    for (int pass = 0; pass < 8; ++pass) {
        f32x16 acc[2][2];
        #pragma unroll
        for (int rt = 0; rt < 2; rt++)
            #pragma unroll
            for (int r = 0; r < 16; r++) {
                acc[rt][0][r] = -hcv[pass][0];
                acc[rt][1][r] = -hcv[pass][1];
            }

        #pragma unroll
        for (int kc = 0; kc < 4; ++kc) {
            const int i   = pass * 4 + kc;
            const int cs  = kc & 1;          // current frag set (literal per unroll)
            const int ns  = cs ^ 1;          // next frag set

            // frags(i) landed (issued last step); Bs[i&1] reads done -> safe overwrite
            __builtin_amdgcn_s_waitcnt(WAIT_LGKM0);

            if (i + 2 < 32) {
                stageB(i + 2);
                __builtin_amdgcn_s_waitcnt(WAIT_VM4);    // stage(i+1) complete
            } else if (i + 1 < 32) {
                __builtin_amdgcn_s_waitcnt(WAIT_VM0);    // last stage complete
            }

            if (i + 1 < 32) {
                // issue ds_reads for step i+1 BEFORE this step's MFMAs
                const char* ab = As[(kc + 1) & 3];
                const char* bb = Bs[(i + 1) & 1][w];
                #pragma unroll
                for (int rt = 0; rt < 2; rt++) {
                    const int rbase = (rt * 32 + l32) * 64;
                    af[ns][rt][0].v = *(const u32x4*)(ab + rbase + p0 * 16);
                    af[ns][rt][1].v = *(const u32x4*)(ab + rbase + p1 * 16);
                }
                #pragma unroll
                for (int ct = 0; ct < 2; ct++) {
                    const int cbase = (ct * 32 + l32) * 64;
                    bf[ns][ct][0].v = *(const u32x4*)(bb + cbase + p0 * 16);
                    bf[ns][ct][1].v = *(const u32x4*)(bb + cbase + p1 * 16);
                }
            }

            // MFMAs for step i use frag set cs — already resident, no wait
            #pragma unroll
            for (int q = 0; q < 2; q++)
                #pragma unroll
                for (int hf = 0; hf < 2; hf++)
                    #pragma unroll
                    for (int rt = 0; rt < 2; rt++)
                        #pragma unroll
                        for (int ct = 0; ct < 2; ct++)
                            acc[rt][ct] = __builtin_amdgcn_mfma_f32_32x32x16_fp8_fp8(
                                af[cs][rt][q].l[hf], bf[cs][ct][q].l[hf],
                                acc[rt][ct], 0, 0, 0);
        }

        // fold pass into running max (pack 11-bit code id into low mantissa bits)
        #pragma unroll
        for (int ct = 0; ct < 2; ct++) {
            const unsigned code = (unsigned)(pass * 256 + w * 64 + ct * 32 + l32);
            #pragma unroll
            for (int rt = 0; rt < 2; rt++)
                #pragma unroll
                for (int r = 0; r < 16; r++) {
                    unsigned u = (__float_as_uint(acc[rt][ct][r]) & 0xFFFFF800u) | code;
                    mp[rt][r] = fmaxf(mp[rt][r], __uint_as_float(u));
                }
        }
    }

    // ---- cross-lane argmax over the 32 lanes sharing each output row ----
    #pragma unroll
    for (int m = 1; m <= 16; m <<= 1)
        #pragma unroll
        for (int rt = 0; rt < 2; rt++)
            #pragma unroll
            for (int r = 0; r < 16; r++)
                mp[rt][r] = fmaxf(mp[rt][r], __shfl_xor(mp[rt][r], m, 64));

    if (l32 == 0) {
        #pragma unroll
        for (int rt = 0; rt < 2; rt++)
            #pragma unroll
            for (int r = 0; r < 16; r++) {
                const int row = rt * 32 + (r & 3) + 8 * (r >> 2) + 4 * h;
                red[row][w] = mp[rt][r];
            }
    }
    __syncthreads();
    if (t < 64) {
        float b0 = fmaxf(fmaxf(red[t][0], red[t][1]), fmaxf(red[t][2], red[t][3]));
        idxs[t] = (int)(__float_as_uint(b0) & 2047u);
    }
    __syncthreads();

    // ---- fused gather (fp32 codebook) + loss partial ----
    float lsum = 0.0f;
    #pragma unroll 4
    for (int r = 0; r < 64; r++) {
        const int code = idxs[r];
        const float c  = cb[(size_t)code * DIM + t];
        const float xv = x[(size_t)(row0 + r) * DIM + t];
        out[(size_t)(row0 + r) * DIM + t] = c;
        const float d = xv - c;
        lsum += d * d;
    }
    #pragma unroll
    for (int o = 32; o > 0; o >>= 1) lsum += __shfl_down(lsum, o, 64);
    if (lane == 0) lred[w] = lsum;
    __syncthreads();
    if (t == 0) {
        const float scale = 1.25f / (float)((size_t)N_ROWS * DIM);  // (beta+1)/(N*D)
        atomicAdd(loss, (lred[0] + lred[1] + lred[2] + lred[3]) * scale);
    }
}

extern "C" void kernel_launch(void* const* d_in, const int* in_sizes, int n_in,
                              void* d_out, int out_size, void* d_ws, size_t ws_size,
                              hipStream_t stream) {
    const float* x  = (const float*)d_in[0];
    const float* cb = (const float*)d_in[1];
    float* out  = (float*)d_out;
    float* loss = out + (size_t)N_ROWS * DIM;

    char* ws = (char*)d_ws;
    unsigned int* cbf8 = (unsigned int*)ws;                        // 512 KB
    float* halfcn = (float*)(ws + (size_t)KCODES * 256);           // 8 KB

    prep_cb<<<KCODES / 4, 256, 0, stream>>>(cb, cbf8, halfcn, loss);
    vq_fused<<<N_ROWS / 64, 256, 0, stream>>>(x, cb, (const char*)cbf8, halfcn, out, loss);
}